// Round 3
// baseline (779.917 us; speedup 1.0000x reference)
//
#include <hip/hip_runtime.h>

// ---------------------------------------------------------------------------
// SpatioTemporalBlock: biLSTM -> temporal MHA -> (collapsed) GAT -> fusion
// B=16 S=128 F=64 H=256 HEADS=4 DH=64 AH=128 D2=512
// ALL float tensors are FP32 (per reference); edge_index int32 (unused:
// GAT attention collapses to uniform alpha because node features are
// broadcast-identical; exp(e-m)=1 exactly, segment sums = h_common).
// Internally: MFMA operands converted f32->bf16 at LDS staging; all VALU
// math and outputs in f32.
// ---------------------------------------------------------------------------

typedef unsigned short u16;
typedef __bf16 bf16x8 __attribute__((ext_vector_type(8)));
typedef float f32x4 __attribute__((ext_vector_type(4)));
typedef unsigned short ushort8v __attribute__((ext_vector_type(8)));
typedef unsigned short ushort4v __attribute__((ext_vector_type(4)));

#define BN_INV_F 0.9999950000374997f

__device__ __forceinline__ u16 f2b(float f) {
  union { float f; unsigned int i; } v;
  v.f = f;
  unsigned int x = v.i;
  unsigned int r = (x + 0x7FFFu + ((x >> 16) & 1u)) >> 16;
  return (u16)r;
}
__device__ __forceinline__ f32x4 mfma16(ushort8v a, ushort8v b, f32x4 c) {
  return __builtin_amdgcn_mfma_f32_16x16x32_bf16(
      __builtin_bit_cast(bf16x8, a), __builtin_bit_cast(bf16x8, b), c, 0, 0, 0);
}
__device__ __forceinline__ float sigm(float x) { return 1.f / (1.f + __expf(-x)); }
__device__ __forceinline__ float tanh_f(float x) {
  float e = __expf(2.f * x);
  return 1.f - 2.f / (e + 1.f);
}

// ---------------------------------------------------------------------------
// Kernel 1: bidirectional LSTM. grid = 32 blocks: dir = bx>>4, chunk q = bx&15.
// WG owns h-cols [q*16, q*16+16): 64 gate rows; Whh slice (64x256) + Wih slice
// (64x64) staged f32->bf16 into LDS once. Per step: 10 MFMA, f32 gate math,
// bf16 h broadcast via global hbuf, flag release/acquire across the 16 WGs.
// ---------------------------------------------------------------------------
__global__ __launch_bounds__(256) void lstm_kernel(
    const float* __restrict__ x,
    const float* __restrict__ Wih0, const float* __restrict__ Whh0,
    const float* __restrict__ bih0, const float* __restrict__ bhh0,
    const float* __restrict__ Wih1, const float* __restrict__ Whh1,
    const float* __restrict__ bih1, const float* __restrict__ bhh1,
    u16* __restrict__ hbuf,   // [2 parity][2 dir][16][256] bf16
    int* __restrict__ flags,  // [2][16]
    u16* __restrict__ tb)     // [16][128][512] bf16
{
  const int tid = threadIdx.x;
  const int bx = blockIdx.x;
  const int d = bx >> 4;
  const int q = bx & 15;
  const float* Wih = d ? Wih1 : Wih0;
  const float* Whh = d ? Whh1 : Whh0;
  const float* bih = d ? bih1 : bih0;
  const float* bhh = d ? bhh1 : bhh0;

  __shared__ u16 whh_s[64][264];
  __shared__ u16 wih_s[64][72];
  __shared__ u16 h_s[16][264];
  __shared__ u16 x_s[16][72];
  __shared__ float z_s[4][16][17];
  __shared__ float bias_s[64];

  {
    int r = tid >> 2, seg = tid & 3;
    int grow = ((r >> 4) << 8) + q * 16 + (r & 15);
    const float4* src = (const float4*)(Whh + grow * 256 + seg * 64);
#pragma unroll
    for (int i = 0; i < 16; i++) {
      float4 v = src[i];
      whh_s[r][seg * 64 + i * 4 + 0] = f2b(v.x);
      whh_s[r][seg * 64 + i * 4 + 1] = f2b(v.y);
      whh_s[r][seg * 64 + i * 4 + 2] = f2b(v.z);
      whh_s[r][seg * 64 + i * 4 + 3] = f2b(v.w);
    }
    const float4* src2 = (const float4*)(Wih + grow * 64 + seg * 16);
#pragma unroll
    for (int i = 0; i < 4; i++) {
      float4 v = src2[i];
      wih_s[r][seg * 16 + i * 4 + 0] = f2b(v.x);
      wih_s[r][seg * 16 + i * 4 + 1] = f2b(v.y);
      wih_s[r][seg * 16 + i * 4 + 2] = f2b(v.z);
      wih_s[r][seg * 16 + i * 4 + 3] = f2b(v.w);
    }
  }
  if (tid < 64) {
    int grow = ((tid >> 4) << 8) + q * 16 + (tid & 15);
    bias_s[tid] = bih[grow] + bhh[grow];
  }

  const int w = tid >> 6;
  const int ln = tid & 63;
  const int col16 = ln & 15;
  const int quad = ln >> 4;
  const int eb = tid >> 4;  // elementwise: batch
  const int ec = tid & 15;  // elementwise: h-col within chunk
  float c_reg = 0.f;

  for (int t = 0; t < 128; t++) {
    const int pos = d ? (127 - t) : t;
    {
      int b_ = tid >> 4;
      int f0 = (tid & 15) * 4;
      float4 xv = *(const float4*)(x + (b_ * 128 + pos) * 64 + f0);
      x_s[b_][f0 + 0] = f2b(xv.x);
      x_s[b_][f0 + 1] = f2b(xv.y);
      x_s[b_][f0 + 2] = f2b(xv.z);
      x_s[b_][f0 + 3] = f2b(xv.w);
      int c0 = (tid & 15) * 16;
      const u16* hsrc = hbuf + (((t & 1) * 2 + d) * 16 + b_) * 256 + c0;
      *(ushort8v*)&h_s[b_][c0] = *(const ushort8v*)(hsrc);
      *(ushort8v*)&h_s[b_][c0 + 8] = *(const ushort8v*)(hsrc + 8);
    }
    __syncthreads();

    f32x4 acc = {0.f, 0.f, 0.f, 0.f};
#pragma unroll
    for (int kt = 0; kt < 2; kt++) {
      ushort8v av = *(const ushort8v*)&x_s[col16][kt * 32 + quad * 8];
      ushort8v bv = *(const ushort8v*)&wih_s[w * 16 + col16][kt * 32 + quad * 8];
      acc = mfma16(av, bv, acc);
    }
#pragma unroll
    for (int kt = 0; kt < 8; kt++) {
      ushort8v av = *(const ushort8v*)&h_s[col16][kt * 32 + quad * 8];
      ushort8v bv = *(const ushort8v*)&whh_s[w * 16 + col16][kt * 32 + quad * 8];
      acc = mfma16(av, bv, acc);
    }
#pragma unroll
    for (int reg = 0; reg < 4; reg++)
      z_s[w][quad * 4 + reg][col16] = acc[reg];
    __syncthreads();

    // gates: torch order i, f, g, o
    float zi = z_s[0][eb][ec] + bias_s[ec];
    float zf = z_s[1][eb][ec] + bias_s[16 + ec];
    float zg = z_s[2][eb][ec] + bias_s[32 + ec];
    float zo = z_s[3][eb][ec] + bias_s[48 + ec];
    float si = sigm(zi), sf = sigm(zf), so = sigm(zo);
    float tg = tanh_f(zg);
    c_reg = sf * c_reg + si * tg;
    float hv = so * tanh_f(c_reg);
    u16 hb16 = f2b(hv);
    hbuf[((((t + 1) & 1) * 2 + d) * 16 + eb) * 256 + q * 16 + ec] = hb16;
    tb[(eb * 128 + pos) * 512 + d * 256 + q * 16 + ec] = hb16;

    if (t != 127) {
      __syncthreads();  // drains vmem (compiler emits vmcnt(0) before barrier)
      if (tid == 0) {
        __builtin_amdgcn_fence(__ATOMIC_RELEASE, "agent");
        __hip_atomic_store(&flags[d * 16 + q], t + 1, __ATOMIC_RELAXED,
                           __HIP_MEMORY_SCOPE_AGENT);
      }
      const int idx = d * 16 + (ln & 15);
      for (;;) {
        int v = __hip_atomic_load(&flags[idx], __ATOMIC_RELAXED,
                                  __HIP_MEMORY_SCOPE_AGENT);
        if (__ballot(v >= t + 1) == ~0ull) break;
        __builtin_amdgcn_s_sleep(1);
      }
      __builtin_amdgcn_fence(__ATOMIC_ACQUIRE, "agent");
    }
  }
}

// ---------------------------------------------------------------------------
// Kernel 2: QKV projection.  out = t @ W^T + bias, M=2048 N=512 K=512.
// grid = (32 Mtiles, 8 Ntiles, 3 which). Q,K stored bf16 (feed MFMA);
// V stored f32 (feeds VALU GEMV).
// ---------------------------------------------------------------------------
__global__ __launch_bounds__(256) void qkv_kernel(
    const u16* __restrict__ tb,
    const float* __restrict__ Wq, const float* __restrict__ bq,
    const float* __restrict__ Wk, const float* __restrict__ bk,
    const float* __restrict__ Wv, const float* __restrict__ bv,
    u16* __restrict__ Qb, u16* __restrict__ Kb, float* __restrict__ Vb)
{
  const int tid = threadIdx.x;
  const int bxm = blockIdx.x, byn = blockIdx.y, bz = blockIdx.z;
  const float* W = (bz == 0) ? Wq : ((bz == 1) ? Wk : Wv);
  const float* bias = (bz == 0) ? bq : ((bz == 1) ? bk : bv);

  __shared__ u16 a_s[64][40];
  __shared__ u16 b_s[64][40];
  const int w = tid >> 6, ln = tid & 63, col16 = ln & 15, quad = ln >> 4;

  f32x4 acc[4];
#pragma unroll
  for (int n = 0; n < 4; n++) acc[n] = (f32x4){0.f, 0.f, 0.f, 0.f};

  for (int kt = 0; kt < 16; kt++) {
    int r = tid >> 2, seg = tid & 3;
    *(ushort8v*)&a_s[r][seg * 8] =
        *(const ushort8v*)(tb + (bxm * 64 + r) * 512 + kt * 32 + seg * 8);
    const float4* wsrc = (const float4*)(W + (byn * 64 + r) * 512 + kt * 32 + seg * 8);
    float4 w0 = wsrc[0], w1 = wsrc[1];
    b_s[r][seg * 8 + 0] = f2b(w0.x);
    b_s[r][seg * 8 + 1] = f2b(w0.y);
    b_s[r][seg * 8 + 2] = f2b(w0.z);
    b_s[r][seg * 8 + 3] = f2b(w0.w);
    b_s[r][seg * 8 + 4] = f2b(w1.x);
    b_s[r][seg * 8 + 5] = f2b(w1.y);
    b_s[r][seg * 8 + 6] = f2b(w1.z);
    b_s[r][seg * 8 + 7] = f2b(w1.w);
    __syncthreads();
    ushort8v av = *(const ushort8v*)&a_s[w * 16 + col16][quad * 8];
#pragma unroll
    for (int n = 0; n < 4; n++) {
      ushort8v bvv = *(const ushort8v*)&b_s[n * 16 + col16][quad * 8];
      acc[n] = mfma16(av, bvv, acc[n]);
    }
    __syncthreads();
  }
#pragma unroll
  for (int n = 0; n < 4; n++) {
    float bs = bias[byn * 64 + n * 16 + col16];
#pragma unroll
    for (int reg = 0; reg < 4; reg++) {
      int row = bxm * 64 + w * 16 + quad * 4 + reg;
      int col = byn * 64 + n * 16 + col16;
      if (bz == 2)
        Vb[row * 512 + col] = acc[n][reg] + bs;
      else if (bz == 1)
        Kb[row * 512 + col] = f2b(acc[n][reg] + bs);
      else
        Qb[row * 512 + col] = f2b(acc[n][reg] + bs);
    }
  }
}

// ---------------------------------------------------------------------------
// Kernel 3: scores + softmax -> attn (d_out, f32). grid = (16 b, 4 h, 2 qhalf).
// ---------------------------------------------------------------------------
__global__ __launch_bounds__(256) void attn_kernel(
    const u16* __restrict__ Qb, const u16* __restrict__ Kb,
    float* __restrict__ attn_out)
{
  const int b = blockIdx.x, h = blockIdx.y, half = blockIdx.z;
  const int tid = threadIdx.x;
  __shared__ __align__(16) char smem[52224];
  u16 (*q_s)[136] = (u16(*)[136])smem;
  u16 (*k_s)[136] = (u16(*)[136])(smem + 17408);
  float (*sc)[132] = (float(*)[132])smem;  // reused after MFMA

  const int w = tid >> 6, ln = tid & 63, col16 = ln & 15, quad = ln >> 4;
  {
    int r = tid >> 2, seg = tid & 3;
    const u16* src = Qb + (b * 128 + half * 64 + r) * 512 + h * 128 + seg * 32;
#pragma unroll
    for (int i = 0; i < 4; i++)
      *(ushort8v*)&q_s[r][seg * 32 + i * 8] = *(const ushort8v*)(src + i * 8);
    int r2 = tid >> 1, sg = tid & 1;
    const u16* src2 = Kb + (b * 128 + r2) * 512 + h * 128 + sg * 64;
#pragma unroll
    for (int i = 0; i < 8; i++)
      *(ushort8v*)&k_s[r2][sg * 64 + i * 8] = *(const ushort8v*)(src2 + i * 8);
  }
  __syncthreads();

  f32x4 acc[8];
#pragma unroll
  for (int n = 0; n < 8; n++) acc[n] = (f32x4){0.f, 0.f, 0.f, 0.f};
#pragma unroll
  for (int kd = 0; kd < 4; kd++) {
    ushort8v av = *(const ushort8v*)&q_s[w * 16 + col16][kd * 32 + quad * 8];
#pragma unroll
    for (int n = 0; n < 8; n++) {
      ushort8v bvv = *(const ushort8v*)&k_s[n * 16 + col16][kd * 32 + quad * 8];
      acc[n] = mfma16(av, bvv, acc[n]);
    }
  }
  __syncthreads();  // done with q_s/k_s before overwriting with sc
  const float scale = 0.08838834764831845f;  // 1/sqrt(128)
#pragma unroll
  for (int n = 0; n < 8; n++)
#pragma unroll
    for (int reg = 0; reg < 4; reg++)
      sc[w * 16 + quad * 4 + reg][n * 16 + col16] = acc[n][reg] * scale;
  __syncthreads();

  const int row = tid >> 2, p = tid & 3;
  float m = -1e30f;
  for (int c0 = 0; c0 < 32; c0++) m = fmaxf(m, sc[row][p * 32 + c0]);
  m = fmaxf(m, __shfl_xor(m, 1));
  m = fmaxf(m, __shfl_xor(m, 2));
  float s = 0.f;
  for (int c0 = 0; c0 < 32; c0++) {
    float e = __expf(sc[row][p * 32 + c0] - m);
    sc[row][p * 32 + c0] = e;
    s += e;
  }
  s += __shfl_xor(s, 1);
  s += __shfl_xor(s, 2);
  float inv = 1.f / s;
  float* orow = attn_out + ((b * 4 + h) * 128 + half * 64 + row) * 128 + p * 32;
  for (int c0 = 0; c0 < 32; c0++) orow[c0] = sc[row][p * 32 + c0] * inv;
}

// ---------------------------------------------------------------------------
// Kernel 4: ao (q=127 only) + last = ao @ Wo^T + bo.  grid = 16 (batch).
// ---------------------------------------------------------------------------
__global__ __launch_bounds__(256) void aolast_kernel(
    const float* __restrict__ attn, const float* __restrict__ Vb,
    const float* __restrict__ Wo, const float* __restrict__ bo,
    float* __restrict__ last_ws)
{
  const int b = blockIdx.x, tid = threadIdx.x;
  __shared__ float arow[4][128];
  __shared__ float ao_s[512];
#pragma unroll
  for (int e = 0; e < 2; e++) {
    int idx = tid + e * 256;
    int h = idx >> 7, k = idx & 127;
    arow[h][k] = attn[((b * 4 + h) * 128 + 127) * 128 + k];
  }
  __syncthreads();
#pragma unroll
  for (int pass = 0; pass < 2; pass++) {
    int d2 = tid + pass * 256;
    int hh = d2 >> 7;
    float acc = 0.f;
    for (int k = 0; k < 128; k++)
      acc += arow[hh][k] * Vb[(b * 128 + k) * 512 + d2];
    ao_s[d2] = acc;
  }
  __syncthreads();
#pragma unroll
  for (int pass = 0; pass < 2; pass++) {
    int j = tid + pass * 256;
    float acc = bo[j];
    const float4* Wo4 = (const float4*)(Wo + j * 512);
    for (int k4 = 0; k4 < 128; k4++) {
      float4 wv = Wo4[k4];
      acc += ao_s[k4 * 4 + 0] * wv.x + ao_s[k4 * 4 + 1] * wv.y +
             ao_s[k4 * 4 + 2] * wv.z + ao_s[k4 * 4 + 3] * wv.w;
    }
    last_ws[b * 512 + j] = acc;
  }
}

// ---------------------------------------------------------------------------
// Kernel 5: collapsed GAT (2 dense layers) + fusion Linear + LayerNorm + ReLU.
// grid = 16 (batch), 256 threads (one per output feature).
// ---------------------------------------------------------------------------
__global__ __launch_bounds__(256) void fuse_kernel(
    const float* __restrict__ last_ws,
    const float* __restrict__ W1, const float* __restrict__ b1,
    const float* __restrict__ g1, const float* __restrict__ be1,
    const float* __restrict__ W2, const float* __restrict__ pb2,
    const float* __restrict__ g2, const float* __restrict__ be2,
    const float* __restrict__ Wf, const float* __restrict__ bfv,
    const float* __restrict__ ln_g, const float* __restrict__ ln_b,
    float* __restrict__ dout)
{
  const int b = blockIdx.x, tid = threadIdx.x;
  __shared__ float last_s[512];
  __shared__ float h_s2[256];
  __shared__ float red_s[4];
  last_s[tid] = last_ws[b * 512 + tid];
  last_s[tid + 256] = last_ws[b * 512 + tid + 256];
  __syncthreads();

  const int j = tid;
  float acc = 0.f;
  for (int k = 0; k < 512; k++) acc += last_s[k] * W1[k * 256 + j];
  float u = (acc + b1[j]) * BN_INV_F * g1[j] + be1[j];
  float h1 = u > 0.f ? u : expm1f(u);
  h_s2[j] = h1;
  __syncthreads();

  float acc2 = 0.f;
  for (int k = 0; k < 256; k++) acc2 += h_s2[k] * W2[k * 256 + j];
  float u2 = (acc2 + pb2[j]) * BN_INV_F * g2[j] + be2[j];
  float sp = u2 > 0.f ? u2 : expm1f(u2);
  __syncthreads();
  h_s2[j] = sp;
  __syncthreads();

  float f = bfv[j];
  const float4* Wf4 = (const float4*)(Wf + j * 768);
  for (int k4 = 0; k4 < 128; k4++) {
    float4 wv = Wf4[k4];
    f += last_s[k4 * 4 + 0] * wv.x + last_s[k4 * 4 + 1] * wv.y +
         last_s[k4 * 4 + 2] * wv.z + last_s[k4 * 4 + 3] * wv.w;
  }
  for (int k4 = 0; k4 < 64; k4++) {
    float4 wv = Wf4[128 + k4];
    f += h_s2[k4 * 4 + 0] * wv.x + h_s2[k4 * 4 + 1] * wv.y +
         h_s2[k4 * 4 + 2] * wv.z + h_s2[k4 * 4 + 3] * wv.w;
  }

  float v = f;
#pragma unroll
  for (int o = 32; o > 0; o >>= 1) v += __shfl_xor(v, o);
  if ((tid & 63) == 0) red_s[tid >> 6] = v;
  __syncthreads();
  float mu = (red_s[0] + red_s[1] + red_s[2] + red_s[3]) * (1.f / 256.f);
  float dv = f - mu;
  float vv = dv * dv;
#pragma unroll
  for (int o = 32; o > 0; o >>= 1) vv += __shfl_xor(vv, o);
  __syncthreads();
  if ((tid & 63) == 0) red_s[tid >> 6] = vv;
  __syncthreads();
  float var = (red_s[0] + red_s[1] + red_s[2] + red_s[3]) * (1.f / 256.f);
  float y = dv * rsqrtf(var + 1e-5f) * ln_g[j] + ln_b[j];
  dout[b * 256 + j] = fmaxf(y, 0.f);
}

// ---------------------------------------------------------------------------
// ws layout (bytes):
//   0        hbuf   [2][2][16][256] bf16   32768
//   32768    flags  [32] int               128     (memset [0,32896) each call)
//   33024    last   [16][512] f32          32768
//   66048    tb     [16][128][512] bf16    2097152
//   2163200  Q      [2048][512] bf16       2097152
//   4260352  K      [2048][512] bf16       2097152
//   6357504  V      [2048][512] f32        4194304  -> total 10551808 bytes
// ---------------------------------------------------------------------------
extern "C" void kernel_launch(void* const* d_in, const int* in_sizes, int n_in,
                              void* d_out, int out_size, void* d_ws, size_t ws_size,
                              hipStream_t stream) {
  (void)in_sizes; (void)n_in; (void)out_size; (void)ws_size;
  const float* x     = (const float*)d_in[0];
  const float* Wih_f = (const float*)d_in[2];
  const float* Whh_f = (const float*)d_in[3];
  const float* bih_f = (const float*)d_in[4];
  const float* bhh_f = (const float*)d_in[5];
  const float* Wih_b = (const float*)d_in[6];
  const float* Whh_b = (const float*)d_in[7];
  const float* bih_b = (const float*)d_in[8];
  const float* bhh_b = (const float*)d_in[9];
  const float* Wq = (const float*)d_in[10]; const float* bq = (const float*)d_in[11];
  const float* Wk = (const float*)d_in[12]; const float* bk = (const float*)d_in[13];
  const float* Wv = (const float*)d_in[14]; const float* bv = (const float*)d_in[15];
  const float* Wo = (const float*)d_in[16]; const float* bo = (const float*)d_in[17];
  const float* W1 = (const float*)d_in[18];
  const float* b1 = (const float*)d_in[21];
  const float* g1 = (const float*)d_in[22]; const float* be1 = (const float*)d_in[23];
  const float* W2 = (const float*)d_in[24];
  const float* pb2 = (const float*)d_in[27];
  const float* g2 = (const float*)d_in[28]; const float* be2 = (const float*)d_in[29];
  const float* Wf = (const float*)d_in[30]; const float* bfv = (const float*)d_in[31];
  const float* ln_g = (const float*)d_in[32]; const float* ln_b = (const float*)d_in[33];

  float* dout = (float*)d_out;
  char* ws = (char*)d_ws;
  u16*   hbuf    = (u16*)(ws + 0);
  int*   flags   = (int*)(ws + 32768);
  float* last_ws = (float*)(ws + 33024);
  u16*   tb      = (u16*)(ws + 66048);
  u16*   Qb      = (u16*)(ws + 2163200);
  u16*   Kb      = (u16*)(ws + 4260352);
  float* Vb      = (float*)(ws + 6357504);

  (void)hipMemsetAsync(ws, 0, 32896, stream);  // h init (=0) + flags
  lstm_kernel<<<32, 256, 0, stream>>>(x, Wih_f, Whh_f, bih_f, bhh_f,
                                      Wih_b, Whh_b, bih_b, bhh_b,
                                      hbuf, flags, tb);
  qkv_kernel<<<dim3(32, 8, 3), 256, 0, stream>>>(tb, Wq, bq, Wk, bk, Wv, bv,
                                                 Qb, Kb, Vb);
  attn_kernel<<<dim3(16, 4, 2), 256, 0, stream>>>(Qb, Kb, dout + 4096);
  aolast_kernel<<<16, 256, 0, stream>>>(dout + 4096, Vb, Wo, bo, last_ws);
  fuse_kernel<<<16, 256, 0, stream>>>(last_ws, W1, b1, g1, be1,
                                      W2, pb2, g2, be2,
                                      Wf, bfv, ln_g, ln_b, dout);
}

// Round 4
// 562.290 us; speedup vs baseline: 1.3870x; 1.3870x over previous
//
#include <hip/hip_runtime.h>

// ---------------------------------------------------------------------------
// SpatioTemporalBlock: biLSTM -> temporal MHA -> (collapsed) GAT -> fusion
// B=16 S=128 F=64 H=256 HEADS=4 DH=64 AH=128 D2=512
// FP32 inputs/outputs; MFMA operands converted f32->bf16 at staging.
// GAT collapses: broadcast node features => uniform alpha => dense layers.
// LSTM cross-WG sync: poison-word protocol. hbuf is a write-once ring
// [128 steps][2 dir][16 b][256 c] bf16, memset 0xFF per launch. h published
// as packed u32 via relaxed agent atomics (MALL-coherent, no fences); readers
// poll until != 0xFFFFFFFF (h bounded by sigmoid/tanh => never NaN pattern).
// ---------------------------------------------------------------------------

typedef unsigned short u16;
typedef unsigned int u32;
typedef __bf16 bf16x8 __attribute__((ext_vector_type(8)));
typedef float f32x4 __attribute__((ext_vector_type(4)));
typedef unsigned short ushort8v __attribute__((ext_vector_type(8)));

#define BN_INV_F 0.9999950000374997f
#define POISON 0xFFFFFFFFu

__device__ __forceinline__ float b2f(u16 u) {
  union { float f; unsigned int i; } v;
  v.i = ((unsigned int)u) << 16;
  return v.f;
}
__device__ __forceinline__ u16 f2b(float f) {
  union { float f; unsigned int i; } v;
  v.f = f;
  unsigned int x = v.i;
  unsigned int r = (x + 0x7FFFu + ((x >> 16) & 1u)) >> 16;
  return (u16)r;
}
__device__ __forceinline__ f32x4 mfma16(ushort8v a, ushort8v b, f32x4 c) {
  return __builtin_amdgcn_mfma_f32_16x16x32_bf16(
      __builtin_bit_cast(bf16x8, a), __builtin_bit_cast(bf16x8, b), c, 0, 0, 0);
}
__device__ __forceinline__ float sigm(float x) { return 1.f / (1.f + __expf(-x)); }
__device__ __forceinline__ float tanh_f(float x) {
  float e = __expf(2.f * x);
  return 1.f - 2.f / (e + 1.f);
}

// ---------------------------------------------------------------------------
// Kernel 1: bidirectional LSTM. grid = 32 blocks: dir = bx>>4, chunk q = bx&15.
// WG owns h-cols [q*16, q*16+16): 64 gate rows; Whh (64x256) + Wih (64x64)
// staged f32->bf16 into LDS once. Per step: poll h(t) words, 10 MFMA, f32
// gate math, publish h(t+1) chunk via relaxed agent atomic u32 stores.
// ---------------------------------------------------------------------------
__global__ __launch_bounds__(256) void lstm_kernel(
    const float* __restrict__ x,
    const float* __restrict__ Wih0, const float* __restrict__ Whh0,
    const float* __restrict__ bih0, const float* __restrict__ bhh0,
    const float* __restrict__ Wih1, const float* __restrict__ Whh1,
    const float* __restrict__ bih1, const float* __restrict__ bhh1,
    u32* __restrict__ hbuf,   // [128][2][16][128] u32 view (poisoned 0xFF)
    u16* __restrict__ tb)     // [16][128][512] bf16
{
  const int tid = threadIdx.x;
  const int bx = blockIdx.x;
  const int d = bx >> 4;
  const int q = bx & 15;
  const float* Wih = d ? Wih1 : Wih0;
  const float* Whh = d ? Whh1 : Whh0;
  const float* bih = d ? bih1 : bih0;
  const float* bhh = d ? bhh1 : bhh0;

  __shared__ u16 whh_s[64][264];
  __shared__ u16 wih_s[64][72];
  __shared__ u16 h_s[16][264];
  __shared__ u16 x_s[16][72];
  __shared__ float z_s[4][16][17];
  __shared__ float bias_s[64];

  {
    int r = tid >> 2, seg = tid & 3;
    int grow = ((r >> 4) << 8) + q * 16 + (r & 15);
    const float4* src = (const float4*)(Whh + grow * 256 + seg * 64);
#pragma unroll
    for (int i = 0; i < 16; i++) {
      float4 v = src[i];
      whh_s[r][seg * 64 + i * 4 + 0] = f2b(v.x);
      whh_s[r][seg * 64 + i * 4 + 1] = f2b(v.y);
      whh_s[r][seg * 64 + i * 4 + 2] = f2b(v.z);
      whh_s[r][seg * 64 + i * 4 + 3] = f2b(v.w);
    }
    const float4* src2 = (const float4*)(Wih + grow * 64 + seg * 16);
#pragma unroll
    for (int i = 0; i < 4; i++) {
      float4 v = src2[i];
      wih_s[r][seg * 16 + i * 4 + 0] = f2b(v.x);
      wih_s[r][seg * 16 + i * 4 + 1] = f2b(v.y);
      wih_s[r][seg * 16 + i * 4 + 2] = f2b(v.z);
      wih_s[r][seg * 16 + i * 4 + 3] = f2b(v.w);
    }
  }
  if (tid < 64) {
    int grow = ((tid >> 4) << 8) + q * 16 + (tid & 15);
    bias_s[tid] = bih[grow] + bhh[grow];
  }

  const int w = tid >> 6;
  const int ln = tid & 63;
  const int col16 = ln & 15;
  const int quad = ln >> 4;
  const int eb = tid >> 4;  // elementwise: batch
  const int ec = tid & 15;  // elementwise: h-col within chunk
  float c_reg = 0.f;

  for (int t = 0; t < 128; t++) {
    const int pos = d ? (127 - t) : t;
    // stage x(pos) -> bf16 LDS (plain cached loads; overlaps with poll)
    {
      int b_ = tid >> 4;
      int f0 = (tid & 15) * 4;
      float4 xv = *(const float4*)(x + (b_ * 128 + pos) * 64 + f0);
      x_s[b_][f0 + 0] = f2b(xv.x);
      x_s[b_][f0 + 1] = f2b(xv.y);
      x_s[b_][f0 + 2] = f2b(xv.z);
      x_s[b_][f0 + 3] = f2b(xv.w);
    }
    if (t > 0) {
      // poll full h(t): 8 u32 words per thread, until non-poison
      u32* hw = hbuf + (t * 2 + d) * 2048 + (tid >> 4) * 128 + (tid & 15) * 8;
      u32 v[8];
      int pend = 0xFF;
      do {
        int np = 0;
#pragma unroll
        for (int i = 0; i < 8; i++)
          if (pend & (1 << i)) {
            v[i] = __hip_atomic_load(hw + i, __ATOMIC_RELAXED,
                                     __HIP_MEMORY_SCOPE_AGENT);
            if (v[i] == POISON) np |= 1 << i;
          }
        pend = np;
      } while (pend);
      int b_ = tid >> 4, c0 = (tid & 15) * 16;
#pragma unroll
      for (int i = 0; i < 8; i++)
        *(u32*)&h_s[b_][c0 + 2 * i] = v[i];
    }
    __syncthreads();

    f32x4 acc = {0.f, 0.f, 0.f, 0.f};
#pragma unroll
    for (int kt = 0; kt < 2; kt++) {
      ushort8v av = *(const ushort8v*)&x_s[col16][kt * 32 + quad * 8];
      ushort8v bv = *(const ushort8v*)&wih_s[w * 16 + col16][kt * 32 + quad * 8];
      acc = mfma16(av, bv, acc);
    }
    if (t > 0) {
#pragma unroll
      for (int kt = 0; kt < 8; kt++) {
        ushort8v av = *(const ushort8v*)&h_s[col16][kt * 32 + quad * 8];
        ushort8v bv = *(const ushort8v*)&whh_s[w * 16 + col16][kt * 32 + quad * 8];
        acc = mfma16(av, bv, acc);
      }
    }
#pragma unroll
    for (int reg = 0; reg < 4; reg++)
      z_s[w][quad * 4 + reg][col16] = acc[reg];
    __syncthreads();

    // gates: torch order i, f, g, o (f32)
    float zi = z_s[0][eb][ec] + bias_s[ec];
    float zf = z_s[1][eb][ec] + bias_s[16 + ec];
    float zg = z_s[2][eb][ec] + bias_s[32 + ec];
    float zo = z_s[3][eb][ec] + bias_s[48 + ec];
    float si = sigm(zi), sf = sigm(zf), so = sigm(zo);
    float tg = tanh_f(zg);
    c_reg = sf * c_reg + si * tg;
    float hv = so * tanh_f(c_reg);
    u32 my = (u32)f2b(hv);
    u32 hi = __shfl_down((int)my, 1);  // partner col (ec+1), same wave
    if ((ec & 1) == 0) {
      u32 word = my | (hi << 16);
      // tb (plain store; consumed next kernel)
      *(u32*)&tb[(eb * 128 + pos) * 512 + d * 256 + q * 16 + ec] = word;
      if (t < 127) {
        u32* dst = hbuf + ((t + 1) * 2 + d) * 2048 + eb * 128 + (q * 16 + ec) / 2;
        __hip_atomic_store(dst, word, __ATOMIC_RELAXED,
                           __HIP_MEMORY_SCOPE_AGENT);
      }
    }
    // no extra barrier: next-iter writes touch x_s/h_s only, whose reads all
    // completed before the z_s barrier above.
  }
}

// ---------------------------------------------------------------------------
// Kernel 2: QKV projection.  out = t @ W^T + bias, M=2048 N=512 K=512.
// grid = (32 Mtiles, 8 Ntiles, 3 which). Q,K,V stored bf16.
// ---------------------------------------------------------------------------
__global__ __launch_bounds__(256) void qkv_kernel(
    const u16* __restrict__ tb,
    const float* __restrict__ Wq, const float* __restrict__ bq,
    const float* __restrict__ Wk, const float* __restrict__ bk,
    const float* __restrict__ Wv, const float* __restrict__ bv,
    u16* __restrict__ Qb, u16* __restrict__ Kb, u16* __restrict__ Vb)
{
  const int tid = threadIdx.x;
  const int bxm = blockIdx.x, byn = blockIdx.y, bz = blockIdx.z;
  const float* W = (bz == 0) ? Wq : ((bz == 1) ? Wk : Wv);
  const float* bias = (bz == 0) ? bq : ((bz == 1) ? bk : bv);
  u16* outp = (bz == 0) ? Qb : ((bz == 1) ? Kb : Vb);

  __shared__ u16 a_s[64][40];
  __shared__ u16 b_s[64][40];
  const int w = tid >> 6, ln = tid & 63, col16 = ln & 15, quad = ln >> 4;

  f32x4 acc[4];
#pragma unroll
  for (int n = 0; n < 4; n++) acc[n] = (f32x4){0.f, 0.f, 0.f, 0.f};

  for (int kt = 0; kt < 16; kt++) {
    int r = tid >> 2, seg = tid & 3;
    *(ushort8v*)&a_s[r][seg * 8] =
        *(const ushort8v*)(tb + (bxm * 64 + r) * 512 + kt * 32 + seg * 8);
    const float4* wsrc = (const float4*)(W + (byn * 64 + r) * 512 + kt * 32 + seg * 8);
    float4 w0 = wsrc[0], w1 = wsrc[1];
    b_s[r][seg * 8 + 0] = f2b(w0.x);
    b_s[r][seg * 8 + 1] = f2b(w0.y);
    b_s[r][seg * 8 + 2] = f2b(w0.z);
    b_s[r][seg * 8 + 3] = f2b(w0.w);
    b_s[r][seg * 8 + 4] = f2b(w1.x);
    b_s[r][seg * 8 + 5] = f2b(w1.y);
    b_s[r][seg * 8 + 6] = f2b(w1.z);
    b_s[r][seg * 8 + 7] = f2b(w1.w);
    __syncthreads();
    ushort8v av = *(const ushort8v*)&a_s[w * 16 + col16][quad * 8];
#pragma unroll
    for (int n = 0; n < 4; n++) {
      ushort8v bvv = *(const ushort8v*)&b_s[n * 16 + col16][quad * 8];
      acc[n] = mfma16(av, bvv, acc[n]);
    }
    __syncthreads();
  }
#pragma unroll
  for (int n = 0; n < 4; n++) {
    float bs = bias[byn * 64 + n * 16 + col16];
#pragma unroll
    for (int reg = 0; reg < 4; reg++) {
      int row = bxm * 64 + w * 16 + quad * 4 + reg;
      outp[row * 512 + byn * 64 + n * 16 + col16] = f2b(acc[n][reg] + bs);
    }
  }
}

// ---------------------------------------------------------------------------
// Kernel 3: scores + softmax -> attn (d_out, f32). grid = (16 b, 4 h, 2 qhalf).
// ---------------------------------------------------------------------------
__global__ __launch_bounds__(256) void attn_kernel(
    const u16* __restrict__ Qb, const u16* __restrict__ Kb,
    float* __restrict__ attn_out)
{
  const int b = blockIdx.x, h = blockIdx.y, half = blockIdx.z;
  const int tid = threadIdx.x;
  __shared__ __align__(16) char smem[52224];
  u16 (*q_s)[136] = (u16(*)[136])smem;
  u16 (*k_s)[136] = (u16(*)[136])(smem + 17408);
  float (*sc)[132] = (float(*)[132])smem;  // reused after MFMA

  const int w = tid >> 6, ln = tid & 63, col16 = ln & 15, quad = ln >> 4;
  {
    int r = tid >> 2, seg = tid & 3;
    const u16* src = Qb + (b * 128 + half * 64 + r) * 512 + h * 128 + seg * 32;
#pragma unroll
    for (int i = 0; i < 4; i++)
      *(ushort8v*)&q_s[r][seg * 32 + i * 8] = *(const ushort8v*)(src + i * 8);
    int r2 = tid >> 1, sg = tid & 1;
    const u16* src2 = Kb + (b * 128 + r2) * 512 + h * 128 + sg * 64;
#pragma unroll
    for (int i = 0; i < 8; i++)
      *(ushort8v*)&k_s[r2][sg * 64 + i * 8] = *(const ushort8v*)(src2 + i * 8);
  }
  __syncthreads();

  f32x4 acc[8];
#pragma unroll
  for (int n = 0; n < 8; n++) acc[n] = (f32x4){0.f, 0.f, 0.f, 0.f};
#pragma unroll
  for (int kd = 0; kd < 4; kd++) {
    ushort8v av = *(const ushort8v*)&q_s[w * 16 + col16][kd * 32 + quad * 8];
#pragma unroll
    for (int n = 0; n < 8; n++) {
      ushort8v bvv = *(const ushort8v*)&k_s[n * 16 + col16][kd * 32 + quad * 8];
      acc[n] = mfma16(av, bvv, acc[n]);
    }
  }
  __syncthreads();  // done with q_s/k_s before overwriting with sc
  const float scale = 0.08838834764831845f;  // 1/sqrt(128)
#pragma unroll
  for (int n = 0; n < 8; n++)
#pragma unroll
    for (int reg = 0; reg < 4; reg++)
      sc[w * 16 + quad * 4 + reg][n * 16 + col16] = acc[n][reg] * scale;
  __syncthreads();

  const int row = tid >> 2, p = tid & 3;
  float m = -1e30f;
  for (int c0 = 0; c0 < 32; c0++) m = fmaxf(m, sc[row][p * 32 + c0]);
  m = fmaxf(m, __shfl_xor(m, 1));
  m = fmaxf(m, __shfl_xor(m, 2));
  float s = 0.f;
  for (int c0 = 0; c0 < 32; c0++) {
    float e = __expf(sc[row][p * 32 + c0] - m);
    sc[row][p * 32 + c0] = e;
    s += e;
  }
  s += __shfl_xor(s, 1);
  s += __shfl_xor(s, 2);
  float inv = 1.f / s;
  float* orow = attn_out + ((b * 4 + h) * 128 + half * 64 + row) * 128 + p * 32;
  for (int c0 = 0; c0 < 32; c0++) orow[c0] = sc[row][p * 32 + c0] * inv;
}

// ---------------------------------------------------------------------------
// Kernel 4: ao (q=127 only) + last = ao @ Wo^T + bo.  grid = 16 (batch).
// ---------------------------------------------------------------------------
__global__ __launch_bounds__(256) void aolast_kernel(
    const float* __restrict__ attn, const u16* __restrict__ Vb,
    const float* __restrict__ Wo, const float* __restrict__ bo,
    float* __restrict__ last_ws)
{
  const int b = blockIdx.x, tid = threadIdx.x;
  __shared__ float arow[4][128];
  __shared__ float ao_s[512];
#pragma unroll
  for (int e = 0; e < 2; e++) {
    int idx = tid + e * 256;
    int h = idx >> 7, k = idx & 127;
    arow[h][k] = attn[((b * 4 + h) * 128 + 127) * 128 + k];
  }
  __syncthreads();
#pragma unroll
  for (int pass = 0; pass < 2; pass++) {
    int d2 = tid + pass * 256;
    int hh = d2 >> 7;
    float acc = 0.f;
    for (int k = 0; k < 128; k++)
      acc += arow[hh][k] * b2f(Vb[(b * 128 + k) * 512 + d2]);
    ao_s[d2] = acc;
  }
  __syncthreads();
#pragma unroll
  for (int pass = 0; pass < 2; pass++) {
    int j = tid + pass * 256;
    float acc = bo[j];
    const float4* Wo4 = (const float4*)(Wo + j * 512);
    for (int k4 = 0; k4 < 128; k4++) {
      float4 wv = Wo4[k4];
      acc += ao_s[k4 * 4 + 0] * wv.x + ao_s[k4 * 4 + 1] * wv.y +
             ao_s[k4 * 4 + 2] * wv.z + ao_s[k4 * 4 + 3] * wv.w;
    }
    last_ws[b * 512 + j] = acc;
  }
}

// ---------------------------------------------------------------------------
// Kernel 5: collapsed GAT (2 dense layers) + fusion Linear + LayerNorm + ReLU.
// grid = 16 (batch), 256 threads (one per output feature).
// ---------------------------------------------------------------------------
__global__ __launch_bounds__(256) void fuse_kernel(
    const float* __restrict__ last_ws,
    const float* __restrict__ W1, const float* __restrict__ b1,
    const float* __restrict__ g1, const float* __restrict__ be1,
    const float* __restrict__ W2, const float* __restrict__ pb2,
    const float* __restrict__ g2, const float* __restrict__ be2,
    const float* __restrict__ Wf, const float* __restrict__ bfv,
    const float* __restrict__ ln_g, const float* __restrict__ ln_b,
    float* __restrict__ dout)
{
  const int b = blockIdx.x, tid = threadIdx.x;
  __shared__ float last_s[512];
  __shared__ float h_s2[256];
  __shared__ float red_s[4];
  last_s[tid] = last_ws[b * 512 + tid];
  last_s[tid + 256] = last_ws[b * 512 + tid + 256];
  __syncthreads();

  const int j = tid;
  float acc = 0.f;
  for (int k = 0; k < 512; k++) acc += last_s[k] * W1[k * 256 + j];
  float u = (acc + b1[j]) * BN_INV_F * g1[j] + be1[j];
  float h1 = u > 0.f ? u : expm1f(u);
  h_s2[j] = h1;
  __syncthreads();

  float acc2 = 0.f;
  for (int k = 0; k < 256; k++) acc2 += h_s2[k] * W2[k * 256 + j];
  float u2 = (acc2 + pb2[j]) * BN_INV_F * g2[j] + be2[j];
  float sp = u2 > 0.f ? u2 : expm1f(u2);
  __syncthreads();
  h_s2[j] = sp;
  __syncthreads();

  float f = bfv[j];
  const float4* Wf4 = (const float4*)(Wf + j * 768);
  for (int k4 = 0; k4 < 128; k4++) {
    float4 wv = Wf4[k4];
    f += last_s[k4 * 4 + 0] * wv.x + last_s[k4 * 4 + 1] * wv.y +
         last_s[k4 * 4 + 2] * wv.z + last_s[k4 * 4 + 3] * wv.w;
  }
  for (int k4 = 0; k4 < 64; k4++) {
    float4 wv = Wf4[128 + k4];
    f += h_s2[k4 * 4 + 0] * wv.x + h_s2[k4 * 4 + 1] * wv.y +
         h_s2[k4 * 4 + 2] * wv.z + h_s2[k4 * 4 + 3] * wv.w;
  }

  float v = f;
#pragma unroll
  for (int o = 32; o > 0; o >>= 1) v += __shfl_xor(v, o);
  if ((tid & 63) == 0) red_s[tid >> 6] = v;
  __syncthreads();
  float mu = (red_s[0] + red_s[1] + red_s[2] + red_s[3]) * (1.f / 256.f);
  float dv = f - mu;
  float vv = dv * dv;
#pragma unroll
  for (int o = 32; o > 0; o >>= 1) vv += __shfl_xor(vv, o);
  __syncthreads();
  if ((tid & 63) == 0) red_s[tid >> 6] = vv;
  __syncthreads();
  float var = (red_s[0] + red_s[1] + red_s[2] + red_s[3]) * (1.f / 256.f);
  float y = dv * rsqrtf(var + 1e-5f) * ln_g[j] + ln_b[j];
  dout[b * 256 + j] = fmaxf(y, 0.f);
}

// ---------------------------------------------------------------------------
// ws layout (bytes):
//   0         hbuf  [128][2][16][256] bf16  2097152  (memset 0xFF each call)
//   2097152   last  [16][512] f32           32768
//   2129920   tb    [16][128][512] bf16     2097152
//   4227072   Q     [2048][512] bf16        2097152
//   6324224   K     [2048][512] bf16        2097152
//   8421376   V     [2048][512] bf16        2097152  -> total 10518528 bytes
// ---------------------------------------------------------------------------
extern "C" void kernel_launch(void* const* d_in, const int* in_sizes, int n_in,
                              void* d_out, int out_size, void* d_ws, size_t ws_size,
                              hipStream_t stream) {
  (void)in_sizes; (void)n_in; (void)out_size; (void)ws_size;
  const float* x     = (const float*)d_in[0];
  const float* Wih_f = (const float*)d_in[2];
  const float* Whh_f = (const float*)d_in[3];
  const float* bih_f = (const float*)d_in[4];
  const float* bhh_f = (const float*)d_in[5];
  const float* Wih_b = (const float*)d_in[6];
  const float* Whh_b = (const float*)d_in[7];
  const float* bih_b = (const float*)d_in[8];
  const float* bhh_b = (const float*)d_in[9];
  const float* Wq = (const float*)d_in[10]; const float* bq = (const float*)d_in[11];
  const float* Wk = (const float*)d_in[12]; const float* bk = (const float*)d_in[13];
  const float* Wv = (const float*)d_in[14]; const float* bv = (const float*)d_in[15];
  const float* Wo = (const float*)d_in[16]; const float* bo = (const float*)d_in[17];
  const float* W1 = (const float*)d_in[18];
  const float* b1 = (const float*)d_in[21];
  const float* g1 = (const float*)d_in[22]; const float* be1 = (const float*)d_in[23];
  const float* W2 = (const float*)d_in[24];
  const float* pb2 = (const float*)d_in[27];
  const float* g2 = (const float*)d_in[28]; const float* be2 = (const float*)d_in[29];
  const float* Wf = (const float*)d_in[30]; const float* bfv = (const float*)d_in[31];
  const float* ln_g = (const float*)d_in[32]; const float* ln_b = (const float*)d_in[33];

  float* dout = (float*)d_out;
  char* ws = (char*)d_ws;
  u32*   hbuf    = (u32*)(ws + 0);
  float* last_ws = (float*)(ws + 2097152);
  u16*   tb      = (u16*)(ws + 2129920);
  u16*   Qb      = (u16*)(ws + 4227072);
  u16*   Kb      = (u16*)(ws + 6324224);
  u16*   Vb      = (u16*)(ws + 8421376);

  (void)hipMemsetAsync(ws, 0xFF, 2097152, stream);  // poison hbuf ring
  lstm_kernel<<<32, 256, 0, stream>>>(x, Wih_f, Whh_f, bih_f, bhh_f,
                                      Wih_b, Whh_b, bih_b, bhh_b,
                                      hbuf, tb);
  qkv_kernel<<<dim3(32, 8, 3), 256, 0, stream>>>(tb, Wq, bq, Wk, bk, Wv, bv,
                                                 Qb, Kb, Vb);
  attn_kernel<<<dim3(16, 4, 2), 256, 0, stream>>>(Qb, Kb, dout + 4096);
  aolast_kernel<<<16, 256, 0, stream>>>(dout + 4096, Vb, Wo, bo, last_ws);
  fuse_kernel<<<16, 256, 0, stream>>>(last_ws, W1, b1, g1, be1,
                                      W2, pb2, g2, be2,
                                      Wf, bfv, ln_g, ln_b, dout);
}

// Round 5
// 439.639 us; speedup vs baseline: 1.7740x; 1.2790x over previous
//
#include <hip/hip_runtime.h>

// ---------------------------------------------------------------------------
// SpatioTemporalBlock: biLSTM -> temporal MHA -> (collapsed) GAT -> fusion
// B=16 S=128 F=64 H=256 HEADS=4 DH=64 AH=128 D2=512
// FP32 inputs/outputs; MFMA operands converted f32->bf16 at staging.
// GAT collapses: broadcast node features => uniform alpha => dense layers.
// LSTM cross-WG sync: poison-word protocol. hbuf is a write-once ring
// [128 steps][2 dir][16 b][256 c] bf16, memset 0xFF per launch. h published
// as packed u32 via relaxed agent atomics; readers poll with coalesced
// sc1 (device-scope) dwordx4 loads until != 0xFFFFFFFF (h bounded by
// sigmoid*tanh => never the NaN bit pattern).
// ---------------------------------------------------------------------------

typedef unsigned short u16;
typedef unsigned int u32;
typedef __bf16 bf16x8 __attribute__((ext_vector_type(8)));
typedef float f32x4 __attribute__((ext_vector_type(4)));
typedef unsigned short ushort8v __attribute__((ext_vector_type(8)));
typedef unsigned int uint4v __attribute__((ext_vector_type(4)));

#define BN_INV_F 0.9999950000374997f
#define POISON 0xFFFFFFFFu

__device__ __forceinline__ float b2f(u16 u) {
  union { float f; unsigned int i; } v;
  v.i = ((unsigned int)u) << 16;
  return v.f;
}
__device__ __forceinline__ u16 f2b(float f) {
  union { float f; unsigned int i; } v;
  v.f = f;
  unsigned int x = v.i;
  unsigned int r = (x + 0x7FFFu + ((x >> 16) & 1u)) >> 16;
  return (u16)r;
}
__device__ __forceinline__ f32x4 mfma16(ushort8v a, ushort8v b, f32x4 c) {
  return __builtin_amdgcn_mfma_f32_16x16x32_bf16(
      __builtin_bit_cast(bf16x8, a), __builtin_bit_cast(bf16x8, b), c, 0, 0, 0);
}
__device__ __forceinline__ float sigm(float x) { return 1.f / (1.f + __expf(-x)); }
__device__ __forceinline__ float tanh_f(float x) {
  float e = __expf(2.f * x);
  return 1.f - 2.f / (e + 1.f);
}

// ---------------------------------------------------------------------------
// Kernel 1: bidirectional LSTM. grid = 32 blocks: dir = bx>>4, chunk q = bx&15.
// WG owns h-cols [q*16, q*16+16): 64 gate rows; Whh (64x256) + Wih (64x64)
// staged f32->bf16 into LDS once. Per step: poll h(t) via 2 coalesced sc1
// dwordx4 loads/thread, 10 MFMA, f32 gate math, publish h(t+1) chunk via
// relaxed agent atomic u32 stores (write-through to MALL).
// ---------------------------------------------------------------------------
__global__ __launch_bounds__(256) void lstm_kernel(
    const float* __restrict__ x,
    const float* __restrict__ Wih0, const float* __restrict__ Whh0,
    const float* __restrict__ bih0, const float* __restrict__ bhh0,
    const float* __restrict__ Wih1, const float* __restrict__ Whh1,
    const float* __restrict__ bih1, const float* __restrict__ bhh1,
    u32* __restrict__ hbuf,   // [128][2][16][128] u32 view (poisoned 0xFF)
    u16* __restrict__ tb)     // [16][128][512] bf16
{
  const int tid = threadIdx.x;
  const int bx = blockIdx.x;
  const int d = bx >> 4;
  const int q = bx & 15;
  const float* Wih = d ? Wih1 : Wih0;
  const float* Whh = d ? Whh1 : Whh0;
  const float* bih = d ? bih1 : bih0;
  const float* bhh = d ? bhh1 : bhh0;

  __shared__ u16 whh_s[64][264];
  __shared__ u16 wih_s[64][72];
  __shared__ u16 h_s[16][264];
  __shared__ u16 x_s[16][72];
  __shared__ float z_s[4][16][17];
  __shared__ float bias_s[64];

  {
    int r = tid >> 2, seg = tid & 3;
    int grow = ((r >> 4) << 8) + q * 16 + (r & 15);
    const float4* src = (const float4*)(Whh + grow * 256 + seg * 64);
#pragma unroll
    for (int i = 0; i < 16; i++) {
      float4 v = src[i];
      whh_s[r][seg * 64 + i * 4 + 0] = f2b(v.x);
      whh_s[r][seg * 64 + i * 4 + 1] = f2b(v.y);
      whh_s[r][seg * 64 + i * 4 + 2] = f2b(v.z);
      whh_s[r][seg * 64 + i * 4 + 3] = f2b(v.w);
    }
    const float4* src2 = (const float4*)(Wih + grow * 64 + seg * 16);
#pragma unroll
    for (int i = 0; i < 4; i++) {
      float4 v = src2[i];
      wih_s[r][seg * 16 + i * 4 + 0] = f2b(v.x);
      wih_s[r][seg * 16 + i * 4 + 1] = f2b(v.y);
      wih_s[r][seg * 16 + i * 4 + 2] = f2b(v.z);
      wih_s[r][seg * 16 + i * 4 + 3] = f2b(v.w);
    }
  }
  if (tid < 64) {
    int grow = ((tid >> 4) << 8) + q * 16 + (tid & 15);
    bias_s[tid] = bih[grow] + bhh[grow];
  }

  const int w = tid >> 6;
  const int ln = tid & 63;
  const int col16 = ln & 15;
  const int quad = ln >> 4;
  const int eb = tid >> 4;  // elementwise: batch
  const int ec = tid & 15;  // elementwise: h-col within chunk
  float c_reg = 0.f;

  for (int t = 0; t < 128; t++) {
    const int pos = d ? (127 - t) : t;
    // stage x(pos) -> bf16 LDS (plain cached loads)
    {
      int b_ = tid >> 4;
      int f0 = (tid & 15) * 4;
      float4 xv = *(const float4*)(x + (b_ * 128 + pos) * 64 + f0);
      x_s[b_][f0 + 0] = f2b(xv.x);
      x_s[b_][f0 + 1] = f2b(xv.y);
      x_s[b_][f0 + 2] = f2b(xv.z);
      x_s[b_][f0 + 3] = f2b(xv.w);
    }
    if (t > 0) {
      // poll full h(t): 8 u32 words per thread via 2 coalesced sc1 x4 loads
      const u32* hw = hbuf + (t * 2 + d) * 2048 + tid * 8;
      uint4v a, b;
      for (;;) {
        asm volatile(
            "global_load_dwordx4 %0, %2, off sc1\n\t"
            "global_load_dwordx4 %1, %3, off sc1\n\t"
            "s_waitcnt vmcnt(0)"
            : "=v"(a), "=v"(b)
            : "v"(hw), "v"(hw + 4)
            : "memory");
        bool ok = (a.x != POISON) & (a.y != POISON) & (a.z != POISON) &
                  (a.w != POISON) & (b.x != POISON) & (b.y != POISON) &
                  (b.z != POISON) & (b.w != POISON);
        if (ok) break;
      }
      int b_ = tid >> 4, c0 = (tid & 15) * 16;
      *(u32*)&h_s[b_][c0 + 0] = a.x;
      *(u32*)&h_s[b_][c0 + 2] = a.y;
      *(u32*)&h_s[b_][c0 + 4] = a.z;
      *(u32*)&h_s[b_][c0 + 6] = a.w;
      *(u32*)&h_s[b_][c0 + 8] = b.x;
      *(u32*)&h_s[b_][c0 + 10] = b.y;
      *(u32*)&h_s[b_][c0 + 12] = b.z;
      *(u32*)&h_s[b_][c0 + 14] = b.w;
    }
    __syncthreads();

    f32x4 acc = {0.f, 0.f, 0.f, 0.f};
#pragma unroll
    for (int kt = 0; kt < 2; kt++) {
      ushort8v av = *(const ushort8v*)&x_s[col16][kt * 32 + quad * 8];
      ushort8v bv = *(const ushort8v*)&wih_s[w * 16 + col16][kt * 32 + quad * 8];
      acc = mfma16(av, bv, acc);
    }
    if (t > 0) {
#pragma unroll
      for (int kt = 0; kt < 8; kt++) {
        ushort8v av = *(const ushort8v*)&h_s[col16][kt * 32 + quad * 8];
        ushort8v bv = *(const ushort8v*)&whh_s[w * 16 + col16][kt * 32 + quad * 8];
        acc = mfma16(av, bv, acc);
      }
    }
#pragma unroll
    for (int reg = 0; reg < 4; reg++)
      z_s[w][quad * 4 + reg][col16] = acc[reg];
    __syncthreads();

    // gates: torch order i, f, g, o (f32)
    float zi = z_s[0][eb][ec] + bias_s[ec];
    float zf = z_s[1][eb][ec] + bias_s[16 + ec];
    float zg = z_s[2][eb][ec] + bias_s[32 + ec];
    float zo = z_s[3][eb][ec] + bias_s[48 + ec];
    float si = sigm(zi), sf = sigm(zf), so = sigm(zo);
    float tg = tanh_f(zg);
    c_reg = sf * c_reg + si * tg;
    float hv = so * tanh_f(c_reg);
    u32 my = (u32)f2b(hv);
    u32 hi = __shfl_down((int)my, 1);  // partner col (ec+1), same wave
    if ((ec & 1) == 0) {
      u32 word = my | (hi << 16);
      // tb (plain store; consumed next kernel)
      *(u32*)&tb[(eb * 128 + pos) * 512 + d * 256 + q * 16 + ec] = word;
      if (t < 127) {
        u32* dst = hbuf + ((t + 1) * 2 + d) * 2048 + eb * 128 + (q * 16 + ec) / 2;
        __hip_atomic_store(dst, word, __ATOMIC_RELAXED,
                           __HIP_MEMORY_SCOPE_AGENT);
      }
    }
    // no extra barrier: next-iter writes touch x_s/h_s only, whose reads all
    // completed before the z_s barrier above.
  }
}

// ---------------------------------------------------------------------------
// Kernel 2: QKV projection.  out = t @ W^T + bias, M=2048 N=512 K=512.
// grid = (32 Mtiles, 8 Ntiles, 3 which). Q,K,V stored bf16.
// ---------------------------------------------------------------------------
__global__ __launch_bounds__(256) void qkv_kernel(
    const u16* __restrict__ tb,
    const float* __restrict__ Wq, const float* __restrict__ bq,
    const float* __restrict__ Wk, const float* __restrict__ bk,
    const float* __restrict__ Wv, const float* __restrict__ bv,
    u16* __restrict__ Qb, u16* __restrict__ Kb, u16* __restrict__ Vb)
{
  const int tid = threadIdx.x;
  const int bxm = blockIdx.x, byn = blockIdx.y, bz = blockIdx.z;
  const float* W = (bz == 0) ? Wq : ((bz == 1) ? Wk : Wv);
  const float* bias = (bz == 0) ? bq : ((bz == 1) ? bk : bv);
  u16* outp = (bz == 0) ? Qb : ((bz == 1) ? Kb : Vb);

  __shared__ u16 a_s[64][40];
  __shared__ u16 b_s[64][40];
  const int w = tid >> 6, ln = tid & 63, col16 = ln & 15, quad = ln >> 4;

  f32x4 acc[4];
#pragma unroll
  for (int n = 0; n < 4; n++) acc[n] = (f32x4){0.f, 0.f, 0.f, 0.f};

  for (int kt = 0; kt < 16; kt++) {
    int r = tid >> 2, seg = tid & 3;
    *(ushort8v*)&a_s[r][seg * 8] =
        *(const ushort8v*)(tb + (bxm * 64 + r) * 512 + kt * 32 + seg * 8);
    const float4* wsrc = (const float4*)(W + (byn * 64 + r) * 512 + kt * 32 + seg * 8);
    float4 w0 = wsrc[0], w1 = wsrc[1];
    b_s[r][seg * 8 + 0] = f2b(w0.x);
    b_s[r][seg * 8 + 1] = f2b(w0.y);
    b_s[r][seg * 8 + 2] = f2b(w0.z);
    b_s[r][seg * 8 + 3] = f2b(w0.w);
    b_s[r][seg * 8 + 4] = f2b(w1.x);
    b_s[r][seg * 8 + 5] = f2b(w1.y);
    b_s[r][seg * 8 + 6] = f2b(w1.z);
    b_s[r][seg * 8 + 7] = f2b(w1.w);
    __syncthreads();
    ushort8v av = *(const ushort8v*)&a_s[w * 16 + col16][quad * 8];
#pragma unroll
    for (int n = 0; n < 4; n++) {
      ushort8v bvv = *(const ushort8v*)&b_s[n * 16 + col16][quad * 8];
      acc[n] = mfma16(av, bvv, acc[n]);
    }
    __syncthreads();
  }
#pragma unroll
  for (int n = 0; n < 4; n++) {
    float bs = bias[byn * 64 + n * 16 + col16];
#pragma unroll
    for (int reg = 0; reg < 4; reg++) {
      int row = bxm * 64 + w * 16 + quad * 4 + reg;
      outp[row * 512 + byn * 64 + n * 16 + col16] = f2b(acc[n][reg] + bs);
    }
  }
}

// ---------------------------------------------------------------------------
// Kernel 3: scores + softmax -> attn (d_out, f32). grid = (16 b, 4 h, 2 qhalf).
// ---------------------------------------------------------------------------
__global__ __launch_bounds__(256) void attn_kernel(
    const u16* __restrict__ Qb, const u16* __restrict__ Kb,
    float* __restrict__ attn_out)
{
  const int b = blockIdx.x, h = blockIdx.y, half = blockIdx.z;
  const int tid = threadIdx.x;
  __shared__ __align__(16) char smem[52224];
  u16 (*q_s)[136] = (u16(*)[136])smem;
  u16 (*k_s)[136] = (u16(*)[136])(smem + 17408);
  float (*sc)[132] = (float(*)[132])smem;  // reused after MFMA

  const int w = tid >> 6, ln = tid & 63, col16 = ln & 15, quad = ln >> 4;
  {
    int r = tid >> 2, seg = tid & 3;
    const u16* src = Qb + (b * 128 + half * 64 + r) * 512 + h * 128 + seg * 32;
#pragma unroll
    for (int i = 0; i < 4; i++)
      *(ushort8v*)&q_s[r][seg * 32 + i * 8] = *(const ushort8v*)(src + i * 8);
    int r2 = tid >> 1, sg = tid & 1;
    const u16* src2 = Kb + (b * 128 + r2) * 512 + h * 128 + sg * 64;
#pragma unroll
    for (int i = 0; i < 8; i++)
      *(ushort8v*)&k_s[r2][sg * 64 + i * 8] = *(const ushort8v*)(src2 + i * 8);
  }
  __syncthreads();

  f32x4 acc[8];
#pragma unroll
  for (int n = 0; n < 8; n++) acc[n] = (f32x4){0.f, 0.f, 0.f, 0.f};
#pragma unroll
  for (int kd = 0; kd < 4; kd++) {
    ushort8v av = *(const ushort8v*)&q_s[w * 16 + col16][kd * 32 + quad * 8];
#pragma unroll
    for (int n = 0; n < 8; n++) {
      ushort8v bvv = *(const ushort8v*)&k_s[n * 16 + col16][kd * 32 + quad * 8];
      acc[n] = mfma16(av, bvv, acc[n]);
    }
  }
  __syncthreads();  // done with q_s/k_s before overwriting with sc
  const float scale = 0.08838834764831845f;  // 1/sqrt(128)
#pragma unroll
  for (int n = 0; n < 8; n++)
#pragma unroll
    for (int reg = 0; reg < 4; reg++)
      sc[w * 16 + quad * 4 + reg][n * 16 + col16] = acc[n][reg] * scale;
  __syncthreads();

  const int row = tid >> 2, p = tid & 3;
  float m = -1e30f;
  for (int c0 = 0; c0 < 32; c0++) m = fmaxf(m, sc[row][p * 32 + c0]);
  m = fmaxf(m, __shfl_xor(m, 1));
  m = fmaxf(m, __shfl_xor(m, 2));
  float s = 0.f;
  for (int c0 = 0; c0 < 32; c0++) {
    float e = __expf(sc[row][p * 32 + c0] - m);
    sc[row][p * 32 + c0] = e;
    s += e;
  }
  s += __shfl_xor(s, 1);
  s += __shfl_xor(s, 2);
  float inv = 1.f / s;
  float* orow = attn_out + ((b * 4 + h) * 128 + half * 64 + row) * 128 + p * 32;
  for (int c0 = 0; c0 < 32; c0++) orow[c0] = sc[row][p * 32 + c0] * inv;
}

// ---------------------------------------------------------------------------
// Kernel 4 (merged aolast+fuse): ao (q=127 only), last = ao@Wo^T+bo,
// collapsed GAT (2 dense layers), fusion Linear + LayerNorm + ReLU.
// grid = 16 (batch), 256 threads.
// ---------------------------------------------------------------------------
__global__ __launch_bounds__(256) void tail_kernel(
    const float* __restrict__ attn, const u16* __restrict__ Vb,
    const float* __restrict__ Wo, const float* __restrict__ bo,
    const float* __restrict__ W1, const float* __restrict__ b1,
    const float* __restrict__ g1, const float* __restrict__ be1,
    const float* __restrict__ W2, const float* __restrict__ pb2,
    const float* __restrict__ g2, const float* __restrict__ be2,
    const float* __restrict__ Wf, const float* __restrict__ bfv,
    const float* __restrict__ ln_g, const float* __restrict__ ln_b,
    float* __restrict__ dout)
{
  const int b = blockIdx.x, tid = threadIdx.x;
  __shared__ float arow[4][128];
  __shared__ float ao_s[512];
  __shared__ float last_s[512];
  __shared__ float h_s2[256];
  __shared__ float red_s[4];

  // ---- ao row (q=127) ----
#pragma unroll
  for (int e = 0; e < 2; e++) {
    int idx = tid + e * 256;
    int h = idx >> 7, k = idx & 127;
    arow[h][k] = attn[((b * 4 + h) * 128 + 127) * 128 + k];
  }
  __syncthreads();
#pragma unroll
  for (int pass = 0; pass < 2; pass++) {
    int d2 = tid + pass * 256;
    int hh = d2 >> 7;
    float acc = 0.f;
    for (int k = 0; k < 128; k++)
      acc += arow[hh][k] * b2f(Vb[(b * 128 + k) * 512 + d2]);
    ao_s[d2] = acc;
  }
  __syncthreads();
  // ---- last = ao @ Wo^T + bo ----
#pragma unroll
  for (int pass = 0; pass < 2; pass++) {
    int j = tid + pass * 256;
    float acc = bo[j];
    const float4* Wo4 = (const float4*)(Wo + j * 512);
    for (int k4 = 0; k4 < 128; k4++) {
      float4 wv = Wo4[k4];
      acc += ao_s[k4 * 4 + 0] * wv.x + ao_s[k4 * 4 + 1] * wv.y +
             ao_s[k4 * 4 + 2] * wv.z + ao_s[k4 * 4 + 3] * wv.w;
    }
    last_s[j] = acc;
  }
  __syncthreads();

  // ---- collapsed GAT layer 1 ----
  const int j = tid;
  float acc = 0.f;
  for (int k = 0; k < 512; k++) acc += last_s[k] * W1[k * 256 + j];
  float u = (acc + b1[j]) * BN_INV_F * g1[j] + be1[j];
  float h1 = u > 0.f ? u : expm1f(u);
  h_s2[j] = h1;
  __syncthreads();

  // ---- collapsed GAT layer 2 ----
  float acc2 = 0.f;
  for (int k = 0; k < 256; k++) acc2 += h_s2[k] * W2[k * 256 + j];
  float u2 = (acc2 + pb2[j]) * BN_INV_F * g2[j] + be2[j];
  float sp = u2 > 0.f ? u2 : expm1f(u2);
  __syncthreads();
  h_s2[j] = sp;
  __syncthreads();

  // ---- fusion Linear ----
  float f = bfv[j];
  const float4* Wf4 = (const float4*)(Wf + j * 768);
  for (int k4 = 0; k4 < 128; k4++) {
    float4 wv = Wf4[k4];
    f += last_s[k4 * 4 + 0] * wv.x + last_s[k4 * 4 + 1] * wv.y +
         last_s[k4 * 4 + 2] * wv.z + last_s[k4 * 4 + 3] * wv.w;
  }
  for (int k4 = 0; k4 < 64; k4++) {
    float4 wv = Wf4[128 + k4];
    f += h_s2[k4 * 4 + 0] * wv.x + h_s2[k4 * 4 + 1] * wv.y +
         h_s2[k4 * 4 + 2] * wv.z + h_s2[k4 * 4 + 3] * wv.w;
  }

  // ---- LayerNorm + ReLU ----
  float v = f;
#pragma unroll
  for (int o = 32; o > 0; o >>= 1) v += __shfl_xor(v, o);
  if ((tid & 63) == 0) red_s[tid >> 6] = v;
  __syncthreads();
  float mu = (red_s[0] + red_s[1] + red_s[2] + red_s[3]) * (1.f / 256.f);
  float dv = f - mu;
  float vv = dv * dv;
#pragma unroll
  for (int o = 32; o > 0; o >>= 1) vv += __shfl_xor(vv, o);
  __syncthreads();
  if ((tid & 63) == 0) red_s[tid >> 6] = vv;
  __syncthreads();
  float var = (red_s[0] + red_s[1] + red_s[2] + red_s[3]) * (1.f / 256.f);
  float y = dv * rsqrtf(var + 1e-5f) * ln_g[j] + ln_b[j];
  dout[b * 256 + j] = fmaxf(y, 0.f);
}

// ---------------------------------------------------------------------------
// ws layout (bytes):
//   0         hbuf  [128][2][16][256] bf16  2097152  (memset 0xFF each call)
//   2129920   tb    [16][128][512] bf16     2097152
//   4227072   Q     [2048][512] bf16        2097152
//   6324224   K     [2048][512] bf16        2097152
//   8421376   V     [2048][512] bf16        2097152  -> total 10518528 bytes
// ---------------------------------------------------------------------------
extern "C" void kernel_launch(void* const* d_in, const int* in_sizes, int n_in,
                              void* d_out, int out_size, void* d_ws, size_t ws_size,
                              hipStream_t stream) {
  (void)in_sizes; (void)n_in; (void)out_size; (void)ws_size;
  const float* x     = (const float*)d_in[0];
  const float* Wih_f = (const float*)d_in[2];
  const float* Whh_f = (const float*)d_in[3];
  const float* bih_f = (const float*)d_in[4];
  const float* bhh_f = (const float*)d_in[5];
  const float* Wih_b = (const float*)d_in[6];
  const float* Whh_b = (const float*)d_in[7];
  const float* bih_b = (const float*)d_in[8];
  const float* bhh_b = (const float*)d_in[9];
  const float* Wq = (const float*)d_in[10]; const float* bq = (const float*)d_in[11];
  const float* Wk = (const float*)d_in[12]; const float* bk = (const float*)d_in[13];
  const float* Wv = (const float*)d_in[14]; const float* bv = (const float*)d_in[15];
  const float* Wo = (const float*)d_in[16]; const float* bo = (const float*)d_in[17];
  const float* W1 = (const float*)d_in[18];
  const float* b1 = (const float*)d_in[21];
  const float* g1 = (const float*)d_in[22]; const float* be1 = (const float*)d_in[23];
  const float* W2 = (const float*)d_in[24];
  const float* pb2 = (const float*)d_in[27];
  const float* g2 = (const float*)d_in[28]; const float* be2 = (const float*)d_in[29];
  const float* Wf = (const float*)d_in[30]; const float* bfv = (const float*)d_in[31];
  const float* ln_g = (const float*)d_in[32]; const float* ln_b = (const float*)d_in[33];

  float* dout = (float*)d_out;
  char* ws = (char*)d_ws;
  u32* hbuf = (u32*)(ws + 0);
  u16* tb   = (u16*)(ws + 2129920);
  u16* Qb   = (u16*)(ws + 4227072);
  u16* Kb   = (u16*)(ws + 6324224);
  u16* Vb   = (u16*)(ws + 8421376);

  (void)hipMemsetAsync(ws, 0xFF, 2097152, stream);  // poison hbuf ring
  lstm_kernel<<<32, 256, 0, stream>>>(x, Wih_f, Whh_f, bih_f, bhh_f,
                                      Wih_b, Whh_b, bih_b, bhh_b,
                                      hbuf, tb);
  qkv_kernel<<<dim3(32, 8, 3), 256, 0, stream>>>(tb, Wq, bq, Wk, bk, Wv, bv,
                                                 Qb, Kb, Vb);
  attn_kernel<<<dim3(16, 4, 2), 256, 0, stream>>>(Qb, Kb, dout + 4096);
  tail_kernel<<<16, 256, 0, stream>>>(dout + 4096, Vb, Wo, bo,
                                      W1, b1, g1, be1, W2, pb2, g2, be2,
                                      Wf, bfv, ln_g, ln_b, dout);
}